// Round 8
// baseline (293.217 us; speedup 1.0000x reference)
//
#include <hip/hip_runtime.h>
#include <hip/hip_bf16.h>

#define CIN 32
#define COUT 64
#define SEGS 8
#define SCHUNK 1024

typedef __attribute__((ext_vector_type(8))) short bf16x8;
typedef __attribute__((ext_vector_type(4))) float f32x4;

__device__ inline short bf16r(float x) {
    unsigned u = __float_as_uint(x);
    return (short)((u + 0x7FFFu + ((u >> 16) & 1u)) >> 16);
}

__device__ inline unsigned pk2(float lo, float hi) {
    __hip_bfloat162 t = __float22bfloat162_rn(make_float2(lo, hi));
    return *(unsigned*)&t;
}

// ---------------------------------------------------------------------------
// Fused prep: [0,32) pack weights | [32,32+nbm) gather out_bxyz |
// rest: build 80B featb rows = 32 bf16 feats + bf16 pb.xyz + pad.
__global__ void prep_kernel(const float* __restrict__ W1,
                            const float* __restrict__ W2,
                            short* __restrict__ wpack,
                            const float4* __restrict__ bxyz4,
                            const int* __restrict__ sidx,
                            float4* __restrict__ out_bxyz,
                            const float* __restrict__ feat,
                            uint4* __restrict__ featb,
                            int M, int N, int nbm) {
    int b = blockIdx.x, tid = threadIdx.x;
    if (b < 32) {
        int t = b * 256 + tid;                 // 8192 exactly
        int e = t & 7, l = (t >> 3) & 63, f = t >> 9;
        int g = l >> 4, n16 = l & 15;
        int kc = (f & 7) >> 2, nt = f & 3;
        int k = kc * 32 + g * 8 + e;
        int n = nt * 16 + n16;
        float v;
        if (f < 8) v = (k < CIN + 3) ? W1[k * COUT + n] : 0.f;
        else       v = W2[k * COUT + n];
        wpack[t] = bf16r(v);
    } else if (b < 32 + nbm) {
        int i = (b - 32) * 256 + tid;
        if (i < M) out_bxyz[i] = bxyz4[sidx[i]];
    } else {
        int p = (b - 32 - nbm) * 256 + tid;
        if (p < N) {
            const float4* s = (const float4*)(feat + (size_t)p * CIN);
            float4 f0 = s[0], f1 = s[1], f2 = s[2], f3 = s[3];
            float4 f4 = s[4], f5 = s[5], f6 = s[6], f7 = s[7];
            float4 pb = bxyz4[p];
            uint4* d = featb + (size_t)p * 5;
            d[0] = make_uint4(pk2(f0.x, f0.y), pk2(f0.z, f0.w), pk2(f1.x, f1.y), pk2(f1.z, f1.w));
            d[1] = make_uint4(pk2(f2.x, f2.y), pk2(f2.z, f2.w), pk2(f3.x, f3.y), pk2(f3.z, f3.w));
            d[2] = make_uint4(pk2(f4.x, f4.y), pk2(f4.z, f4.w), pk2(f5.x, f5.y), pk2(f5.z, f5.w));
            d[3] = make_uint4(pk2(f6.x, f6.y), pk2(f6.z, f6.w), pk2(f7.x, f7.y), pk2(f7.z, f7.w));
            d[4] = make_uint4(pk2(pb.y, pb.z), pk2(pb.w, 0.f), 0u, 0u);
        }
    }
}

// ---------------------------------------------------------------------------
// Ticketing: one returning-atomic pass; loc[e] = within-segment position.
__global__ void histloc_kernel(const int4* __restrict__ e_new4,
                               int* __restrict__ counts,
                               int4* __restrict__ loc4, int E8) {
    int i = blockIdx.x * blockDim.x + threadIdx.x;
    if (i >= E8) return;
    int4 a = e_new4[i * 2];
    int4 b = e_new4[i * 2 + 1];
    int4 la, lb;
    la.x = atomicAdd(&counts[a.x], 1);
    la.y = atomicAdd(&counts[a.y], 1);
    la.z = atomicAdd(&counts[a.z], 1);
    la.w = atomicAdd(&counts[a.w], 1);
    lb.x = atomicAdd(&counts[b.x], 1);
    lb.y = atomicAdd(&counts[b.y], 1);
    lb.z = atomicAdd(&counts[b.z], 1);
    lb.w = atomicAdd(&counts[b.w], 1);
    loc4[i * 2]     = la;
    loc4[i * 2 + 1] = lb;
}

// ---------------------------------------------------------------------------
__global__ void scanA_kernel(const int* __restrict__ counts,
                             int* __restrict__ row1,
                             int* __restrict__ sums, int M) {
    __shared__ int lds[256];
    int t = threadIdx.x, blk = blockIdx.x;
    int base = blk * SCHUNK + t * 4;
    int v0 = (base + 0 < M) ? counts[base + 0] : 0;
    int v1 = (base + 1 < M) ? counts[base + 1] : 0;
    int v2 = (base + 2 < M) ? counts[base + 2] : 0;
    int v3 = (base + 3 < M) ? counts[base + 3] : 0;
    int s = v0 + v1 + v2 + v3;
    int val = s;
    lds[t] = val; __syncthreads();
    for (int off = 1; off < 256; off <<= 1) {
        int x = (t >= off) ? lds[t - off] : 0;
        __syncthreads();
        val += x; lds[t] = val;
        __syncthreads();
    }
    int ex = val - s;
    if (base + 0 < M) row1[base + 0] = ex + v0;
    if (base + 1 < M) row1[base + 1] = ex + v0 + v1;
    if (base + 2 < M) row1[base + 2] = ex + v0 + v1 + v2;
    if (base + 3 < M) row1[base + 3] = ex + s;
    if (t == 255) sums[blk] = val;
}

// scanC with scanB folded in: each block sums sums[0..blk) itself (nchunks<=256).
__global__ void scanC_kernel(int* __restrict__ row1,
                             const int* __restrict__ sums,
                             int* __restrict__ row_start, int M) {
    __shared__ int lds[256];
    int blk = blockIdx.x, t = threadIdx.x;
    lds[t] = (t < blk) ? sums[t] : 0;
    __syncthreads();
    for (int off = 128; off > 0; off >>= 1) {
        if (t < off) lds[t] += lds[t + off];
        __syncthreads();
    }
    int off0 = lds[0];
    if (blk == 0 && t == 0) row_start[0] = 0;
    int base = blk * SCHUNK + t * 4;
#pragma unroll
    for (int i = 0; i < 4; ++i)
        if (base + i < M) row1[base + i] += off0;
}

// ---------------------------------------------------------------------------
__global__ void place_kernel(const int4* __restrict__ e_new4,
                             const int4* __restrict__ e_point4,
                             const int4* __restrict__ loc4,
                             const int* __restrict__ row_start,
                             int* __restrict__ csr_ep, int E8) {
    int i = blockIdx.x * blockDim.x + threadIdx.x;
    if (i >= E8) return;
    int4 n0 = e_new4[i * 2],   n1 = e_new4[i * 2 + 1];
    int4 p0 = e_point4[i * 2], p1 = e_point4[i * 2 + 1];
    int4 l0 = loc4[i * 2],     l1 = loc4[i * 2 + 1];
    csr_ep[row_start[n0.x] + l0.x] = p0.x;
    csr_ep[row_start[n0.y] + l0.y] = p0.y;
    csr_ep[row_start[n0.z] + l0.z] = p0.z;
    csr_ep[row_start[n0.w] + l0.w] = p0.w;
    csr_ep[row_start[n1.x] + l1.x] = p1.x;
    csr_ep[row_start[n1.y] + l1.y] = p1.y;
    csr_ep[row_start[n1.z] + l1.z] = p1.z;
    csr_ep[row_start[n1.w] + l1.w] = p1.w;
}

// ---------------------------------------------------------------------------
// Aggregation: wave = segment stream, 3-slot gather pipeline + double-buffered
// LDS transpose with layer-2 deferred one phase (reads hit a buffer written a
// full phase ago). Swizzle f(r)=((r&4)<<4)|((r&8)<<1): 2-way writes (free),
// uniform 8-lanes/granule b128 reads; XOR bits {4,6} don't collide with the
// per-access offsets {bit7} -> all LDS addrs are base-reg + imm offset.
__global__ __launch_bounds__(256)
void agg_kernel(const uint4* __restrict__ featb,     // [N][5] 16B chunks
                const int* __restrict__ csr_ep,
                const int* __restrict__ row_start,
                const bf16x8* __restrict__ wpack,
                const float* __restrict__ b1,
                const float* __restrict__ b2,
                const float* __restrict__ W1,
                const float4* __restrict__ new_bxyz4,
                float* __restrict__ out_feat, int M) {
    __shared__ char h1buf[4][8192];   // wave-private 2 x 4KB (16x64 f32)
    const int lane = threadIdx.x & 63;
    const int w    = threadIdx.x >> 6;
    const int m    = lane & 15;
    const int g    = lane >> 4;

    int segbase = (blockIdx.x * 4 + w) * SEGS;
    if (segbase >= M) return;
    int segend = min(segbase + SEGS, M);

    bf16x8 w1b[8], w2b[8];
#pragma unroll
    for (int f = 0; f < 8; ++f) w1b[f] = wpack[f * 64 + lane];
#pragma unroll
    for (int f = 0; f < 8; ++f) w2b[f] = wpack[(8 + f) * 64 + lane];

    float b1v[4], b2v[4], w1r0[4], w1r1[4], w1r2[4];
#pragma unroll
    for (int nt = 0; nt < 4; ++nt) {
        int col = nt * 16 + m;
        b1v[nt]  = b1[col];
        b2v[nt]  = b2[col];
        w1r0[nt] = W1[32 * COUT + col];
        w1r1[nt] = W1[33 * COUT + col];
        w1r2[nt] = W1[34 * COUT + col];
    }

    char* h1p = h1buf[w];
    // lane-constant LDS addresses (all per-access variation goes to imm offsets)
    int wA[8];                         // [q*2+ntlo], static-indexed via unroll
#pragma unroll
    for (int q = 0; q < 4; ++q) {
        int row = g * 4 + q;
        int kk = ((row & 4) << 4) | ((row & 8) << 1);
        wA[q * 2 + 0] = (row * 256 + m * 4) ^ kk;
        wA[q * 2 + 1] = (row * 256 + (m + 16) * 4) ^ kk;
    }
    const int fr_m   = ((m & 4) << 4) | ((m & 8) << 1);
    const int rbase0 = (m * 256 + g * 32) ^ fr_m;
    const int rbase1 = (m * 256 + g * 32 + 16) ^ fr_m;

    // ---- cursor (wave-uniform) -------------------------------------------
    int  seg = segbase - 1;
    bool curval = true;
    bool lastF = false;
    int  r1 = row_start[segbase];
    int  c  = r1;
    int  r2 = row_start[min(segbase + 1, M)];

    auto advance = [&]() {
        c += 16;
        while (c >= r1) {
            ++seg;
            if (seg >= segend) { curval = false; return; }
            c = r1; r1 = r2;
            r2 = row_start[min(seg + 2, M)];
            if (c < r1) break;
            out_feat[(size_t)seg * COUT + lane] = 0.f;   // empty segment
        }
        lastF = (c + 16 >= r1);
    };

    f32x4 accv = {0.f, 0.f, 0.f, 0.f};
    int  wb = 0;
    int  segD = 0; bool lastD = false, validD = false;

#define DO_MFMA2()                                                            \
    if (validD) {                                                             \
        const char* hr = h1p + (wb ^ 4096);                                   \
        float4 q0 = *(const float4*)(hr + rbase0);                            \
        float4 q1 = *(const float4*)(hr + rbase1);                            \
        float4 q2 = *(const float4*)(hr + rbase0 + 128);                      \
        float4 q3 = *(const float4*)(hr + rbase1 + 128);                      \
        union { bf16x8 v; unsigned u[4]; } A30, A31;                          \
        A30.u[0] = pk2(q0.x, q0.y); A30.u[1] = pk2(q0.z, q0.w);               \
        A30.u[2] = pk2(q1.x, q1.y); A30.u[3] = pk2(q1.z, q1.w);               \
        A31.u[0] = pk2(q2.x, q2.y); A31.u[1] = pk2(q2.z, q2.w);               \
        A31.u[2] = pk2(q3.x, q3.y); A31.u[3] = pk2(q3.z, q3.w);               \
        _Pragma("unroll")                                                     \
        for (int nt = 0; nt < 4; ++nt) {                                      \
            f32x4 cc = {b2v[nt], b2v[nt], b2v[nt], b2v[nt]};                  \
            cc = __builtin_amdgcn_mfma_f32_16x16x32_bf16(A30.v, w2b[nt], cc, 0, 0, 0); \
            cc = __builtin_amdgcn_mfma_f32_16x16x32_bf16(A31.v, w2b[4 + nt], cc, 0, 0, 0); \
            float t2 = fmaxf(fmaxf(cc[0], cc[1]), fmaxf(cc[2], cc[3]));       \
            accv[nt] = fmaxf(accv[nt], t2);                                   \
        }                                                                     \
        if (lastD) {                                                          \
            _Pragma("unroll")                                                 \
            for (int nt = 0; nt < 4; ++nt) {                                  \
                float v = accv[nt];                                           \
                v = fmaxf(v, __shfl_xor(v, 16));                              \
                v = fmaxf(v, __shfl_xor(v, 32));                              \
                accv[nt] = v;                                                 \
            }                                                                 \
            float outv = (g == 0) ? accv[0] : (g == 1) ? accv[1]              \
                       : (g == 2) ? accv[2] : accv[3];                        \
            out_feat[(size_t)segD * COUT + lane] = outv;                      \
            accv[0] = accv[1] = accv[2] = accv[3] = 0.f;                      \
        }                                                                     \
    }

#define DO_MFMA1(A1, C4X, C4Y, NB)                                            \
    do {                                                                      \
        bf16x8 a2 = {0, 0, 0, 0, 0, 0, 0, 0};                                 \
        if (g == 0) {                                                         \
            a2[0] = (short)(C4X & 0xffffu);                                   \
            a2[1] = (short)(C4X >> 16);                                       \
            a2[2] = (short)(C4Y & 0xffffu);                                   \
        }                                                                     \
        char* hw = h1p + wb;                                                  \
        _Pragma("unroll")                                                     \
        for (int nt = 0; nt < 4; ++nt) {                                      \
            float be = b1v[nt] - NB.y * w1r0[nt] - NB.z * w1r1[nt]            \
                                - NB.w * w1r2[nt];                            \
            f32x4 cc = {be, be, be, be};                                      \
            cc = __builtin_amdgcn_mfma_f32_16x16x32_bf16(A1, w1b[nt], cc, 0, 0, 0); \
            cc = __builtin_amdgcn_mfma_f32_16x16x32_bf16(a2, w1b[4 + nt], cc, 0, 0, 0); \
            _Pragma("unroll")                                                 \
            for (int q = 0; q < 4; ++q)                                       \
                *(float*)(hw + wA[q * 2 + (nt & 1)] + (nt >> 1) * 128) =      \
                    fmaxf(cc[q], 0.f);                                        \
        }                                                                     \
    } while (0)

    // ---- pipeline slots ---------------------------------------------------
    bf16x8 a10, a11, a12;
    unsigned c4x0 = 0, c4y0 = 0, c4x1 = 0, c4y1 = 0, c4x2 = 0, c4y2 = 0;
    int ep0, ep1, ep2;
    int seg0, seg1, seg2;
    bool last0, last1, last2, valid0, valid1, valid2;
    float4 nb0, nb1, nb2;

    advance();
    seg0 = seg; last0 = lastF; valid0 = curval;
    { int iE = valid0 ? min(c + m, r1 - 1) : 0;
      ep0 = csr_ep[iE];
      nb0 = new_bxyz4[valid0 ? min(seg0, M - 1) : 0]; }
    advance();
    seg1 = seg; last1 = lastF; valid1 = curval;
    { int iE = valid1 ? min(c + m, r1 - 1) : 0;
      ep1 = csr_ep[iE];
      nb1 = new_bxyz4[valid1 ? min(seg1, M - 1) : 0]; }
    advance();
    seg2 = seg; last2 = lastF; valid2 = curval;
    { int iE = valid2 ? min(c + m, r1 - 1) : 0;
      ep2 = csr_ep[iE];
      nb2 = new_bxyz4[valid2 ? min(seg2, M - 1) : 0]; }

    {   // prologue featb for slots 0,1
        const uint4* fr = featb + (size_t)(unsigned)ep0 * 5;
        a10 = ((const bf16x8*)fr)[g];
        uint2 t4 = *(const uint2*)(fr + 4); c4x0 = t4.x; c4y0 = t4.y;
    }
    {
        const uint4* fr = featb + (size_t)(unsigned)ep1 * 5;
        a11 = ((const bf16x8*)fr)[g];
        uint2 t4 = *(const uint2*)(fr + 4); c4x1 = t4.x; c4y1 = t4.y;
    }

#define PHASE(I0, I1, I2)                                                     \
    if (!valid##I0) break;                                                    \
    {   /* featb issue for stage p+2 (slot I2) */                             \
        const uint4* fr = featb + (size_t)(unsigned)ep##I2 * 5;               \
        a1##I2 = ((const bf16x8*)fr)[g];                                      \
        uint2 t4 = *(const uint2*)(fr + 4);                                   \
        c4x##I2 = t4.x; c4y##I2 = t4.y;                                       \
    }                                                                         \
    DO_MFMA2();                      /* finish tile t-1 from other buffer */  \
    advance();                                                                \
    {   int tseg = seg; bool tlast = lastF, tval = curval;                    \
        int iE = tval ? min(c + m, r1 - 1) : 0;                               \
        int dseg = seg##I0; bool dlast = last##I0;                            \
        ep##I0 = csr_ep[iE];                   /* stage p+3 into freed slot */\
        DO_MFMA1(a1##I0, c4x##I0, c4y##I0, nb##I0);                           \
        segD = dseg; lastD = dlast; validD = true;                            \
        seg##I0 = tseg; last##I0 = tlast; valid##I0 = tval;                   \
        nb##I0 = new_bxyz4[tval ? min(tseg, M - 1) : 0];                      \
        wb ^= 4096;                                                           \
    }

    for (;;) {
        PHASE(0, 1, 2)
        PHASE(1, 2, 0)
        PHASE(2, 0, 1)
    }

    DO_MFMA2();    // flush the final deferred tile
#undef PHASE
#undef DO_MFMA1
#undef DO_MFMA2
}

// ---------------------------------------------------------------------------
extern "C" void kernel_launch(void* const* d_in, const int* in_sizes, int n_in,
                              void* d_out, int out_size, void* d_ws, size_t ws_size,
                              hipStream_t stream) {
    const float* bxyz   = (const float*)d_in[0];
    const float* feat   = (const float*)d_in[1];
    const int*   sidx   = (const int*)d_in[2];
    const int*   e_pt   = (const int*)d_in[3];
    const int*   e_new  = (const int*)d_in[4];
    const float* W1     = (const float*)d_in[5];
    const float* b1     = (const float*)d_in[6];
    const float* W2     = (const float*)d_in[7];
    const float* b2     = (const float*)d_in[8];

    const int N = in_sizes[0] / 4;
    const int M = in_sizes[2];
    const int E = in_sizes[3];

    float* out_bxyz = (float*)d_out;                 // [M][4]
    float* out_feat = out_bxyz + (size_t)M * 4;      // [M][64]

    // ws layout (16B aligned regions)
    char*  ws        = (char*)d_ws;
    short* wpack     = (short*)ws;                                    // 16 KiB
    size_t off_cnt   = 16384;
    int*   counts    = (int*)(ws + off_cnt);                          // M
    size_t off_row   = off_cnt + (((size_t)M * 4 + 15) & ~(size_t)15);
    int*   row_start = (int*)(ws + off_row);                          // M+4
    size_t off_sums  = off_row + ((((size_t)M + 4) * 4 + 15) & ~(size_t)15);
    int*   sums      = (int*)(ws + off_sums);                         // 256
    size_t off_loc   = off_sums + 1024;
    int*   loc       = (int*)(ws + off_loc);                          // E
    size_t off_csr   = off_loc + (size_t)E * 4;
    int*   csr_ep    = (int*)(ws + off_csr);                          // E
    size_t off_fb    = (off_csr + (size_t)E * 4 + 15) & ~(size_t)15;
    uint4* featb     = (uint4*)(ws + off_fb);                         // N*80B
    int*   row1      = row_start + 1;

    int nbm     = (M + 255) / 256;
    int nbp     = (N + 255) / 256;
    int nchunks = (M + SCHUNK - 1) / SCHUNK;   // 123 for M=125000 (<=256 req.)
    int E8      = E / 8;

    hipMemsetAsync(counts, 0, (size_t)M * 4, stream);

    prep_kernel<<<32 + nbm + nbp, 256, 0, stream>>>(
        W1, W2, wpack, (const float4*)bxyz, sidx, (float4*)out_bxyz,
        feat, featb, M, N, nbm);

    histloc_kernel<<<(E8 + 255) / 256, 256, 0, stream>>>(
        (const int4*)e_new, counts, (int4*)loc, E8);
    scanA_kernel<<<nchunks, 256, 0, stream>>>(counts, row1, sums, M);
    scanC_kernel<<<nchunks, 256, 0, stream>>>(row1, sums, row_start, M);
    place_kernel<<<(E8 + 255) / 256, 256, 0, stream>>>(
        (const int4*)e_new, (const int4*)e_pt, (const int4*)loc,
        row_start, csr_ep, E8);

    int nblocks = (M + 4 * SEGS - 1) / (4 * SEGS);
    agg_kernel<<<nblocks, 256, 0, stream>>>(
        featb, csr_ep, row_start, (const bf16x8*)wpack,
        b1, b2, W1, (const float4*)out_bxyz, out_feat, M);
}